// Round 1
// baseline (5316.498 us; speedup 1.0000x reference)
//
#include <hip/hip_runtime.h>
#include <math.h>

// AlbertLayer fp32 baseline. Workspace requirement ~101 MB.
#define H_ 1024
#define NH_ 16
#define HD_ 64
#define I_ 4096
#define E_ 8
#define B_ 2
#define S_ 2048
#define T_ 4096

#define MAXSLOTS 8704   // 2*T + 8*64 alignment pad
#define MAXTILES 136    // MAXSLOTS/64
#define CH_TILES 32     // row-tiles per MoE chunk (2048 slots)
#define CH_SLOTS 2048
#define NCHUNK 5        // ceil(136/32)

// ---------------- zero ----------------
__global__ void zero_kernel(float* __restrict__ p, int n) {
    int i = blockIdx.x * blockDim.x + threadIdx.x;
    if (i < n) p[i] = 0.f;
}

// ---------------- GEMM ----------------
// MODE 0: C = A@B
// MODE 1: C = A@B + bias
// MODE 2: y1 = gelu(gather(hs)@W1[e])   (chunk-local rows)
// MODE 3: moe_out[tok] += w * (y1@W2[e]) (chunk-local rows, atomic scatter)
template<int MODE>
__global__ __launch_bounds__(256) void gemm_k(
    const float* __restrict__ A, const float* __restrict__ Bw,
    float* __restrict__ C, const float* __restrict__ bias,
    const int* __restrict__ slot_token, const float* __restrict__ slot_w,
    const int* __restrict__ tile_expert, float* __restrict__ moe_out,
    int N, int K, int tile0)
{
    __shared__ float As[16][68];
    __shared__ float Bs[16][68];
    const int bx = blockIdx.x, by = blockIdx.y;
    const int tid = threadIdx.x;
    const int tx = tid & 15, ty = tid >> 4;

    const float* Bp = Bw;
    int gtile = by;
    if (MODE >= 2) {
        gtile = tile0 + by;
        if (gtile >= MAXTILES) return;
        int e = tile_expert[gtile];
        Bp = Bw + (size_t)e * K * N;
    }
    const int n0 = bx * 64;

    float acc[4][4];
    #pragma unroll
    for (int i=0;i<4;i++)
        #pragma unroll
        for (int j=0;j<4;j++) acc[i][j]=0.f;

    for (int k0 = 0; k0 < K; k0 += 16) {
        __syncthreads();
        #pragma unroll
        for (int t=0;t<4;t++) {
            int lin = t*256 + tid;
            int m = lin >> 4, kk = lin & 15;
            float aval;
            if (MODE == 2) {
                int tok = slot_token[gtile*64 + m];
                aval = (tok >= 0) ? A[(size_t)tok*K + k0 + kk] : 0.f;
            } else {
                aval = A[(size_t)(by*64 + m)*K + k0 + kk];
            }
            As[kk][m] = aval;
        }
        #pragma unroll
        for (int t=0;t<4;t++) {
            int lin = t*256 + tid;
            int kk = lin >> 6, n = lin & 63;
            Bs[kk][n] = Bp[(size_t)(k0+kk)*N + n0 + n];
        }
        __syncthreads();
        #pragma unroll
        for (int kk=0; kk<16; ++kk) {
            float a4[4], b4[4];
            #pragma unroll
            for (int i=0;i<4;i++) a4[i] = As[kk][ty*4+i];
            #pragma unroll
            for (int j=0;j<4;j++) b4[j] = Bs[kk][tx*4+j];
            #pragma unroll
            for (int i=0;i<4;i++)
                #pragma unroll
                for (int j=0;j<4;j++)
                    acc[i][j] = fmaf(a4[i], b4[j], acc[i][j]);
        }
    }

    #pragma unroll
    for (int i=0;i<4;i++) {
        int my = ty*4 + i;
        #pragma unroll
        for (int j=0;j<4;j++) {
            int nx = n0 + tx*4 + j;
            float val = acc[i][j];
            if (MODE == 0) {
                C[(size_t)(by*64+my)*N + nx] = val;
            } else if (MODE == 1) {
                C[(size_t)(by*64+my)*N + nx] = val + bias[nx];
            } else if (MODE == 2) {
                C[(size_t)(by*64+my)*N + nx] = 0.5f*val*(1.f + erff(val*0.70710678118654752f));
            } else {
                int slot = gtile*64 + my;
                int tok = slot_token[slot];
                if (tok >= 0) atomicAdd(&moe_out[(size_t)tok*H_ + nx], slot_w[slot]*val);
            }
        }
    }
}

// ---------------- RoPE (in-place on q,k) ----------------
__global__ void rope_kernel(float* __restrict__ q, float* __restrict__ k) {
    int idx = blockIdx.x * blockDim.x + threadIdx.x;  // T*NH*32
    int i = idx & 31;
    int n = (idx >> 5) & (NH_-1);
    int t = idx >> 9;
    int pos = t & (S_ - 1);
    float inv = powf(10000.f, -((float)(2*i) / 64.f));
    float ang = (float)pos * inv;
    float c = cosf(ang), s = sinf(ang);
    size_t base = (size_t)t*H_ + (size_t)n*64;
    float q1 = q[base+i], q2 = q[base+i+32];
    q[base+i]    = q1*c - q2*s;
    q[base+i+32] = q2*c + q1*s;
    float k1 = k[base+i], k2 = k[base+i+32];
    k[base+i]    = k1*c - k2*s;
    k[base+i+32] = k2*c + k1*s;
}

// ---------------- attention: flash-style, 16 q rows/block ----------------
__global__ __launch_bounds__(256) void attn_kernel(
    const float* __restrict__ q, const float* __restrict__ k,
    const float* __restrict__ v, float* __restrict__ ctx)
{
    const int qt = blockIdx.x;
    const int n  = blockIdx.y;
    const int b  = blockIdx.z;
    const int tid = threadIdx.x;
    const int w = tid >> 6;
    const int lane = tid & 63;

    __shared__ float Kt[64*65];          // [d][j] transposed, pad-65
    __shared__ float Vt[64*65];          // [j][d], pad-65
    __shared__ float q_s[4][4][64];
    __shared__ float p_s[4][4][64];

    const size_t headoff = (size_t)b*S_*H_ + (size_t)n*64;

    float mrun[4], lrun[4], acc[4];
    #pragma unroll
    for (int r=0;r<4;r++) {
        int qrow = qt*16 + w*4 + r;
        q_s[w][r][lane] = q[headoff + (size_t)qrow*H_ + lane];
        mrun[r] = -1e30f; lrun[r] = 0.f; acc[r] = 0.f;
    }

    for (int kt=0; kt<S_/64; ++kt) {
        __syncthreads();
        #pragma unroll
        for (int it=0; it<16; ++it) {
            int lin = it*256 + tid;
            int r = lin >> 6, c = lin & 63;
            size_t g = headoff + (size_t)(kt*64+r)*H_ + c;
            Kt[c*65 + r] = k[g];
            Vt[r*65 + c] = v[g];
        }
        __syncthreads();

        // scores: lane j = lane over 64 k-rows of this tile
        float s[4] = {0.f,0.f,0.f,0.f};
        #pragma unroll 16
        for (int d=0; d<64; ++d) {
            float kv = Kt[d*65 + lane];
            #pragma unroll
            for (int r=0;r<4;r++) s[r] = fmaf(q_s[w][r][d], kv, s[r]);
        }
        float alpha[4];
        #pragma unroll
        for (int r=0;r<4;r++) {
            float sv = s[r] * 0.125f;
            float mt = sv;
            #pragma unroll
            for (int off=32; off; off>>=1) mt = fmaxf(mt, __shfl_xor(mt, off));
            float mnew = fmaxf(mrun[r], mt);
            float pv = __expf(sv - mnew);
            float ps = pv;
            #pragma unroll
            for (int off=32; off; off>>=1) ps += __shfl_xor(ps, off);
            alpha[r] = __expf(mrun[r] - mnew);
            lrun[r] = lrun[r]*alpha[r] + ps;
            mrun[r] = mnew;
            p_s[w][r][lane] = pv;
        }
        __syncthreads();   // safety: p_s visible before cross-lane read

        // ctx: lane d = lane over 64 dims
        float add[4] = {0.f,0.f,0.f,0.f};
        #pragma unroll 16
        for (int j=0; j<64; ++j) {
            float vv = Vt[j*65 + lane];
            #pragma unroll
            for (int r=0;r<4;r++) add[r] = fmaf(p_s[w][r][j], vv, add[r]);
        }
        #pragma unroll
        for (int r=0;r<4;r++) acc[r] = acc[r]*alpha[r] + add[r];
    }
    #pragma unroll
    for (int r=0;r<4;r++) {
        int qrow = qt*16 + w*4 + r;
        ctx[headoff + (size_t)qrow*H_ + lane] = acc[r] / lrun[r];
    }
}

// ---------------- layernorm (residual fused) ----------------
__global__ __launch_bounds__(256) void ln_kernel(
    const float* __restrict__ a, const float* __restrict__ res,
    const float* __restrict__ g, const float* __restrict__ beta,
    float* __restrict__ out)
{
    int row = blockIdx.x, tid = threadIdx.x;
    const float4 va = ((const float4*)(a + (size_t)row*H_))[tid];
    const float4 vr = ((const float4*)(res + (size_t)row*H_))[tid];
    float x0=va.x+vr.x, x1=va.y+vr.y, x2=va.z+vr.z, x3=va.w+vr.w;
    float s  = x0+x1+x2+x3;
    float ss = x0*x0 + x1*x1 + x2*x2 + x3*x3;
    #pragma unroll
    for (int off=32; off; off>>=1) { s += __shfl_xor(s, off); ss += __shfl_xor(ss, off); }
    __shared__ float red[8];
    if ((tid&63)==0) { red[tid>>6]=s; red[4+(tid>>6)]=ss; }
    __syncthreads();
    if (tid==0) { red[0]=red[0]+red[1]+red[2]+red[3]; red[4]=red[4]+red[5]+red[6]+red[7]; }
    __syncthreads();
    float mu  = red[0] * (1.f/H_);
    float var = red[4] * (1.f/H_) - mu*mu;
    float rs = rsqrtf(fmaxf(var, 0.f) + 1e-12f);
    const float4 vg = ((const float4*)g)[tid];
    const float4 vb = ((const float4*)beta)[tid];
    float4 vo;
    vo.x = (x0-mu)*rs*vg.x + vb.x;
    vo.y = (x1-mu)*rs*vg.y + vb.y;
    vo.z = (x2-mu)*rs*vg.z + vb.z;
    vo.w = (x3-mu)*rs*vg.w + vb.w;
    ((float4*)(out + (size_t)row*H_))[tid] = vo;
}

// ---------------- router: logits, softmax, top-2, accumulators ----------------
__global__ __launch_bounds__(256) void router_kernel(
    const float* __restrict__ hs, const float* __restrict__ Wg,
    int* __restrict__ tok_e, float* __restrict__ tok_w,
    int* __restrict__ counts, float* __restrict__ P_sum)
{
    int t = blockIdx.x*4 + (threadIdx.x >> 6);
    int lane = threadIdx.x & 63;
    const float* row = hs + (size_t)t * H_;
    float acc[E_];
    #pragma unroll
    for (int e=0;e<E_;e++) acc[e]=0.f;
    for (int it=0; it<16; ++it) {
        int i = it*64 + lane;
        float xv = row[i];
        const float* wg = Wg + (size_t)i*E_;
        #pragma unroll
        for (int e=0;e<E_;e++) acc[e] = fmaf(xv, wg[e], acc[e]);
    }
    #pragma unroll
    for (int e=0;e<E_;e++) {
        float vv = acc[e];
        #pragma unroll
        for (int off=32; off; off>>=1) vv += __shfl_xor(vv, off);
        acc[e] = vv;
    }
    if (lane==0) {
        float mx = acc[0];
        #pragma unroll
        for (int e=1;e<E_;e++) mx = fmaxf(mx, acc[e]);
        float p[E_], se=0.f;
        #pragma unroll
        for (int e=0;e<E_;e++){ p[e] = expf(acc[e]-mx); se += p[e]; }
        float isv = 1.f/se;
        #pragma unroll
        for (int e=0;e<E_;e++){ p[e]*=isv; atomicAdd(&P_sum[e], p[e]); }
        int e1=0;
        #pragma unroll
        for (int e=1;e<E_;e++) if (p[e] > p[e1]) e1=e;     // ties: lowest index (matches lax.top_k)
        int e2 = (e1==0)?1:0;
        #pragma unroll
        for (int e=0;e<E_;e++) if (e!=e1 && p[e] > p[e2]) e2=e;
        float w1=p[e1], w2=p[e2], si=1.f/(w1+w2);
        tok_e[t*2]=e1; tok_e[t*2+1]=e2;
        tok_w[t*2]=w1*si; tok_w[t*2+1]=w2*si;
        atomicAdd(&counts[e1],1); atomicAdd(&counts[e2],1);
    }
}

// ---------------- router finalize: bases, aux loss, slot init ----------------
__global__ void router_finalize(
    const int* __restrict__ counts, const float* __restrict__ P_sum,
    int* __restrict__ base, int* __restrict__ cursor,
    int* __restrict__ slot_token, int* __restrict__ tile_expert,
    float* __restrict__ aux_out)
{
    __shared__ int sbase[E_+1];
    if (threadIdx.x == 0) {
        int bacc = 0;
        float aux = 0.f;
        for (int e=0;e<E_;e++) {
            sbase[e] = bacc; base[e] = bacc;
            bacc += (counts[e] + 63) & ~63;
            cursor[e] = 0;
            aux += ((float)counts[e]/(float)T_) * (P_sum[e]/(float)T_);
        }
        sbase[E_] = bacc; base[E_] = bacc;
        *aux_out = (float)E_ * aux;
    }
    __syncthreads();
    for (int sIdx = (int)threadIdx.x; sIdx < MAXSLOTS; sIdx += (int)blockDim.x)
        slot_token[sIdx] = -1;
    for (int tt = (int)threadIdx.x; tt < MAXTILES; tt += (int)blockDim.x) {
        int s = tt*64;
        int e = E_-1;
        for (int qe=0; qe<E_; ++qe) if (s < sbase[qe+1]) { e = qe; break; }
        tile_expert[tt] = e;
    }
}

// ---------------- scatter tokens into expert slots ----------------
__global__ void scatter_slots(
    const int* __restrict__ tok_e, const float* __restrict__ tok_w,
    const int* __restrict__ base, int* __restrict__ cursor,
    int* __restrict__ slot_token, float* __restrict__ slot_w)
{
    int t = blockIdx.x*blockDim.x + threadIdx.x;
    if (t >= T_) return;
    #pragma unroll
    for (int j=0;j<2;j++) {
        int e = tok_e[t*2+j];
        int pos = atomicAdd(&cursor[e], 1);
        int s = base[e] + pos;
        slot_token[s] = t;
        slot_w[s] = tok_w[t*2+j];
    }
}

extern "C" void kernel_launch(void* const* d_in, const int* in_sizes, int n_in,
                              void* d_out, int out_size, void* d_ws, size_t ws_size,
                              hipStream_t stream)
{
    const float* x    = (const float*)d_in[0];
    const float* Wq   = (const float*)d_in[1];
    const float* Wk   = (const float*)d_in[2];
    const float* Wv   = (const float*)d_in[3];
    const float* Wd   = (const float*)d_in[4];
    const float* bd   = (const float*)d_in[5];
    const float* ln1g = (const float*)d_in[6];
    const float* ln1b = (const float*)d_in[7];
    const float* Wg   = (const float*)d_in[8];
    const float* W1   = (const float*)d_in[9];
    const float* W2   = (const float*)d_in[10];
    const float* ln2g = (const float*)d_in[11];
    const float* ln2b = (const float*)d_in[12];
    float* out = (float*)d_out;

    float* f0 = (float*)d_ws;
    const size_t M4 = (size_t)T_ * H_;          // 4M floats
    float* qb   = f0;                           // q, later attn_out
    float* kb   = f0 + M4;                      // k, later hs
    float* vb   = f0 + 2*M4;                    // v, later moe_out
    float* ctxb = f0 + 3*M4;
    float* y1   = f0 + 4*M4;                    // CH_SLOTS * I_ = 8M floats
    float* misc = f0 + 4*M4 + (size_t)CH_SLOTS*I_;

    int*   tok_e   = (int*)misc;                        // 2*T
    float* tok_w   = misc + 2*T_;                       // 2*T
    int*   slot_tok= (int*)(misc + 4*T_);               // MAXSLOTS
    float* slot_w  = misc + 4*T_ + MAXSLOTS;            // MAXSLOTS
    float* cntf    = misc + 4*T_ + 2*MAXSLOTS;
    int*   counts  = (int*)cntf;                        // 8
    float* P_sum   = cntf + E_;                         // 8
    int*   cursor  = (int*)(cntf + 2*E_);               // 8
    int*   basep   = (int*)(cntf + 3*E_);               // 9
    int*   tile_ex = (int*)(cntf + 3*E_ + (E_+1));      // 136

    dim3 blk(256);

    // QKV projections
    gemm_k<0><<<dim3(H_/64, T_/64), blk, 0, stream>>>(x, Wq, qb, nullptr, nullptr, nullptr, nullptr, nullptr, H_, H_, 0);
    gemm_k<0><<<dim3(H_/64, T_/64), blk, 0, stream>>>(x, Wk, kb, nullptr, nullptr, nullptr, nullptr, nullptr, H_, H_, 0);
    gemm_k<0><<<dim3(H_/64, T_/64), blk, 0, stream>>>(x, Wv, vb, nullptr, nullptr, nullptr, nullptr, nullptr, H_, H_, 0);

    rope_kernel<<<(T_*NH_*32)/256, blk, 0, stream>>>(qb, kb);

    attn_kernel<<<dim3(S_/16, NH_, B_), blk, 0, stream>>>(qb, kb, vb, ctxb);

    // zero moe_out (reuses v buffer; v is consumed) + router accumulators
    zero_kernel<<<(T_*H_)/256, blk, 0, stream>>>(vb, T_*H_);
    zero_kernel<<<1, blk, 0, stream>>>(cntf, 2*E_);

    // attn_out = ctx@Wd + bd   (into q buffer)
    gemm_k<1><<<dim3(H_/64, T_/64), blk, 0, stream>>>(ctxb, Wd, qb, bd, nullptr, nullptr, nullptr, nullptr, H_, H_, 0);

    // hs = LN1(attn_out + x)   (into k buffer)
    ln_kernel<<<T_, blk, 0, stream>>>(qb, x, ln1g, ln1b, kb);

    router_kernel<<<T_/4, blk, 0, stream>>>(kb, Wg, tok_e, tok_w, counts, P_sum);
    router_finalize<<<1, blk, 0, stream>>>(counts, P_sum, basep, cursor, slot_tok, tile_ex, out + (size_t)T_*H_);
    scatter_slots<<<T_/256, blk, 0, stream>>>(tok_e, tok_w, basep, cursor, slot_tok, slot_w);

    // sparse MoE in chunks of 2048 slots
    for (int c=0; c<NCHUNK; ++c) {
        gemm_k<2><<<dim3(I_/64, CH_TILES), blk, 0, stream>>>(kb, W1, y1, nullptr, slot_tok, nullptr, tile_ex, nullptr, I_, H_, c*CH_TILES);
        gemm_k<3><<<dim3(H_/64, CH_TILES), blk, 0, stream>>>(y1, W2, nullptr, nullptr, slot_tok, slot_w, tile_ex, vb, H_, I_, c*CH_TILES);
    }

    // out = LN2(hs + moe_out)
    ln_kernel<<<T_, blk, 0, stream>>>(vb, kb, ln2g, ln2b, out);
}